// Round 9
// baseline (837.695 us; speedup 1.0000x reference)
//
#include <hip/hip_runtime.h>
#include <hip/hip_bf16.h>

#define N_NODES 100000
#define FIN 128
#define HID 16
#define NCLS 40
#define NEDGE 3200000
#define NBUCK 391     // ceil(100000/256): 256 dst-nodes per bucket
#define NCHUNK 782    // ceil(NEDGE/4096)
#define SLICES 4      // sub-blocks per bucket in aggP
#define AGG_LD 17     // LDS stride: 16 channels + degree column
#define XS_LD 132
#define W_LD 132

// ---------------------------------------------------------------------------
// proj1: xw1 = x @ W1[1], xr1 = x @ root1 (both fp32).
// Block: 256 threads, 64 nodes. Thread micro-tile: 4 nodes x 2 cols.
// ---------------------------------------------------------------------------
__global__ __launch_bounds__(256) void proj1_kernel(
    const float* __restrict__ x, const float* __restrict__ W1,
    const float* __restrict__ root1,
    float* __restrict__ xw1, float* __restrict__ xr1) {
  __shared__ float xs[64 * XS_LD];
  __shared__ float WLt[32 * W_LD];

  int tid = threadIdx.x;
  int node0 = blockIdx.x * 64;

  for (int t = tid; t < 32 * FIN; t += 256) {
    int c = t >> 7, i = t & 127;
    WLt[c * W_LD + i] =
        (c < 16) ? W1[FIN * HID + i * HID + c] : root1[i * HID + (c - 16)];
  }
#pragma unroll
  for (int k = 0; k < 8; ++k) {
    int f = k * 256 + tid;
    int r = f >> 5;
    int cw = f & 31;
    float4 v = make_float4(0.f, 0.f, 0.f, 0.f);
    if (node0 + r < N_NODES)
      v = *(const float4*)(x + (size_t)(node0 + r) * FIN + cw * 4);
    *(float4*)(xs + r * XS_LD + cw * 4) = v;
  }
  __syncthreads();

  int tx = tid & 15;
  int ty = tid >> 4;
  const float* w0 = WLt + (2 * tx) * W_LD;
  const float* w1 = w0 + W_LD;
  const float* xrow = xs + (ty * 4) * XS_LD;

  float acc[4][2] = {{0.f, 0.f}, {0.f, 0.f}, {0.f, 0.f}, {0.f, 0.f}};
#pragma unroll 8
  for (int i = 0; i < FIN; i += 4) {
    float4 b0 = *(const float4*)(w0 + i);
    float4 b1v = *(const float4*)(w1 + i);
#pragma unroll
    for (int k = 0; k < 4; ++k) {
      float4 a = *(const float4*)(xrow + k * XS_LD + i);
      acc[k][0] += a.x * b0.x + a.y * b0.y + a.z * b0.z + a.w * b0.w;
      acc[k][1] += a.x * b1v.x + a.y * b1v.y + a.z * b1v.z + a.w * b1v.w;
    }
  }

  int c0 = 2 * tx;
#pragma unroll
  for (int k = 0; k < 4; ++k) {
    int n = node0 + ty * 4 + k;
    if (n < N_NODES) {
      float* dstp = (c0 < 16) ? (xw1 + n * HID + c0) : (xr1 + n * HID + c0 - 16);
      dstp[0] = acc[k][0];
      dstp[1] = acc[k][1];
    }
  }
}

// ---------------------------------------------------------------------------
// histB: bucket histogram (391 counters) with LDS pre-aggregation.
// ---------------------------------------------------------------------------
__global__ __launch_bounds__(256) void histB_kernel(
    const int* __restrict__ dst, int* __restrict__ bcnt) {
  __shared__ int hc[NBUCK];
  for (int t = threadIdx.x; t < NBUCK; t += 256) hc[t] = 0;
  __syncthreads();
  int base = blockIdx.x * 4096;
#pragma unroll
  for (int k = 0; k < 16; ++k) {
    int e = base + k * 256 + threadIdx.x;
    if (e < NEDGE) atomicAdd(&hc[dst[e] >> 8], 1);
  }
  __syncthreads();
  for (int t = threadIdx.x; t < NBUCK; t += 256) {
    int v = hc[t];
    if (v) atomicAdd(&bcnt[t], v);
  }
}

// ---------------------------------------------------------------------------
// scan: exclusive scan of 391 counts -> boff[0..391], gcursor init.
// ---------------------------------------------------------------------------
__global__ __launch_bounds__(512) void scan_kernel(
    const int* __restrict__ bcnt, int* __restrict__ boff,
    int* __restrict__ gcursor) {
  __shared__ int s[512];
  int v = (threadIdx.x < NBUCK) ? bcnt[threadIdx.x] : 0;
  s[threadIdx.x] = v;
  __syncthreads();
  for (int off = 1; off < 512; off <<= 1) {
    int t = (threadIdx.x >= off) ? s[threadIdx.x - off] : 0;
    __syncthreads();
    s[threadIdx.x] += t;
    __syncthreads();
  }
  if (threadIdx.x < NBUCK) {
    int e = s[threadIdx.x] - v;
    boff[threadIdx.x] = e;
    gcursor[threadIdx.x] = e;
  }
  if (threadIdx.x == 0) boff[NBUCK] = NEDGE;
}

// ---------------------------------------------------------------------------
// partA: multi-split partition, 4096-edge chunks. Pass-1 LDS count returns
// the within-(block,bucket) rank (no second LDS-atomic pass). One global
// cursor atomic per (block,bucket). rec = src | (dst&255)<<17.
// ---------------------------------------------------------------------------
__global__ __launch_bounds__(256) void partA_kernel(
    const int* __restrict__ src, const int* __restrict__ dst,
    int* __restrict__ gcursor, unsigned* __restrict__ recs) {
  __shared__ int cnt[NBUCK];
  __shared__ int base[NBUCK];
  for (int t = threadIdx.x; t < NBUCK; t += 256) cnt[t] = 0;
  __syncthreads();

  int ebase = blockIdx.x * 4096;
  unsigned recv[16];
  int bk[16];
  int rank[16];
#pragma unroll
  for (int k = 0; k < 16; ++k) {
    int e = ebase + k * 256 + threadIdx.x;
    if (e < NEDGE) {
      int d = dst[e];
      bk[k] = d >> 8;
      recv[k] = (unsigned)src[e] | ((unsigned)(d & 255) << 17);
      rank[k] = atomicAdd(&cnt[bk[k]], 1);
    } else {
      bk[k] = -1;
    }
  }
  __syncthreads();
  for (int t = threadIdx.x; t < NBUCK; t += 256) {
    int cv = cnt[t];
    base[t] = cv ? atomicAdd(&gcursor[t], cv) : 0;
  }
  __syncthreads();
#pragma unroll
  for (int k = 0; k < 16; ++k)
    if (bk[k] >= 0) recs[base[bk[k]] + rank[k]] = recv[k];
}

// ---------------------------------------------------------------------------
// aggP: bucketed gather-aggregate. Grid = NBUCK*SLICES blocks (full
// occupancy; R6's 391-block version stalled at 26% occupancy). Each block
// handles one contiguous slice of one bucket; 256x17 fp32 LDS tile
// (16 ch + degree col); 2-way unrolled rec/gather loop; flush via global
// atomics (~1/8 of scatter's line-batches).
// ---------------------------------------------------------------------------
template <bool DO_DEG>
__global__ __launch_bounds__(512) void aggP_kernel(
    const int* __restrict__ boff, const unsigned* __restrict__ recs,
    const float* __restrict__ val, float* __restrict__ aggG,
    float* __restrict__ degG) {
  __shared__ float agg[256 * AGG_LD];
  for (int t = threadIdx.x; t < 256 * AGG_LD; t += 512) agg[t] = 0.f;
  __syncthreads();

  int b = blockIdx.x >> 2;   // bucket
  int sl = blockIdx.x & 3;   // slice
  int beg = boff[b], end = boff[b + 1];
  int len = end - beg;
  int js = beg + ((len * sl) >> 2);
  int je = beg + ((len * (sl + 1)) >> 2);

  int g = threadIdx.x >> 4;  // 32 rec-groups
  int c = threadIdx.x & 15;
  int j = js + g;
  for (; j + 32 < je; j += 64) {
    unsigned r0 = recs[j];
    unsigned r1 = recs[j + 32];
    float v0 = val[(r0 & 0x1FFFF) * HID + c];
    float v1 = val[(r1 & 0x1FFFF) * HID + c];
    atomicAdd(&agg[(r0 >> 17) * AGG_LD + c], v0);
    atomicAdd(&agg[(r1 >> 17) * AGG_LD + c], v1);
    if (DO_DEG && c == 0) {
      atomicAdd(&agg[(r0 >> 17) * AGG_LD + 16], 1.0f);
      atomicAdd(&agg[(r1 >> 17) * AGG_LD + 16], 1.0f);
    }
  }
  for (; j < je; j += 32) {
    unsigned r = recs[j];
    float v = val[(r & 0x1FFFF) * HID + c];
    atomicAdd(&agg[(r >> 17) * AGG_LD + c], v);
    if (DO_DEG && c == 0) atomicAdd(&agg[(r >> 17) * AGG_LD + 16], 1.0f);
  }
  __syncthreads();

  int n0 = b * 256;
  for (int t = threadIdx.x; t < 256 * HID; t += 512) {
    int row = t >> 4, cc = t & 15;
    int n = n0 + row;
    if (n < N_NODES) atomicAdd(&aggG[n * HID + cc], agg[row * AGG_LD + cc]);
  }
  if (DO_DEG && threadIdx.x < 256) {
    int n = n0 + threadIdx.x;
    if (n < N_NODES) {
      float dv = agg[threadIdx.x * AGG_LD + 16];
      if (dv != 0.f) atomicAdd(&degG[n], dv);
    }
  }
}

// ---------------------------------------------------------------------------
// hidden: h = elu(agg1/deg + xr1 + b1), float4-vectorized, ceil-grid + guard.
// ---------------------------------------------------------------------------
__global__ __launch_bounds__(256) void hidden_kernel(
    const float4* __restrict__ agg1, const float4* __restrict__ xr1,
    const float* __restrict__ b1, const float* __restrict__ deg,
    float4* __restrict__ h) {
  int t = blockIdx.x * 256 + threadIdx.x;
  if (t >= N_NODES * 4) return;
  int n = t >> 2;
  int q = t & 3;
  float inv = 1.0f / fmaxf(deg[n], 1.0f);
  float4 a = agg1[t];
  float4 r = xr1[t];
  const float4 bb = *(const float4*)(b1 + q * 4);
  float4 o;
  o.x = a.x * inv + r.x + bb.x;
  o.y = a.y * inv + r.y + bb.y;
  o.z = a.z * inv + r.z + bb.z;
  o.w = a.w * inv + r.w + bb.w;
  o.x = (o.x > 0.f) ? o.x : expm1f(o.x);
  o.y = (o.y > 0.f) ? o.y : expm1f(o.y);
  o.z = (o.z > 0.f) ? o.z : expm1f(o.z);
  o.w = (o.w > 0.f) ? o.w : expm1f(o.w);
  h[t] = o;
}

// ---------------------------------------------------------------------------
// out: (agg2/deg) @ W2[1] + h @ root2 + b2, log_softmax, fp32 store.
// ---------------------------------------------------------------------------
__global__ __launch_bounds__(256) void out_kernel(
    const float* __restrict__ h, const float* __restrict__ agg2,
    const float* __restrict__ deg, const float* __restrict__ W2,
    const float* __restrict__ root2, const float* __restrict__ b2v,
    float* __restrict__ out) {
  __shared__ float Wl[HID * NCLS];
  __shared__ float Rl[HID * NCLS];
  __shared__ float Bl[NCLS];
  for (int i = threadIdx.x; i < HID * NCLS; i += blockDim.x) {
    Wl[i] = W2[HID * NCLS + i];
    Rl[i] = root2[i];
  }
  if (threadIdx.x < NCLS) Bl[threadIdx.x] = b2v[threadIdx.x];
  __syncthreads();

  int n = blockIdx.x * blockDim.x + threadIdx.x;
  if (n >= N_NODES) return;

  float inv = 1.0f / fmaxf(deg[n], 1.0f);
  float hv[HID], av[HID];
#pragma unroll
  for (int c = 0; c < HID; ++c) {
    hv[c] = h[n * HID + c];
    av[c] = agg2[n * HID + c] * inv;
  }
  float logit[NCLS];
#pragma unroll
  for (int j = 0; j < NCLS; ++j) logit[j] = Bl[j];
  for (int c = 0; c < HID; ++c) {
    float hc = hv[c], ac = av[c];
#pragma unroll
    for (int j = 0; j < NCLS; ++j)
      logit[j] += ac * Wl[c * NCLS + j] + hc * Rl[c * NCLS + j];
  }
  float m = -INFINITY;
#pragma unroll
  for (int j = 0; j < NCLS; ++j) m = fmaxf(m, logit[j]);
  float s = 0.f;
#pragma unroll
  for (int j = 0; j < NCLS; ++j) s += expf(logit[j] - m);
  float lse = m + logf(s);
#pragma unroll
  for (int j = 0; j < NCLS; ++j)
    out[(size_t)n * NCLS + j] = logit[j] - lse;
}

extern "C" void kernel_launch(void* const* d_in, const int* in_sizes, int n_in,
                              void* d_out, int out_size, void* d_ws,
                              size_t ws_size, hipStream_t stream) {
  const float* x = (const float*)d_in[0];
  const int* ei = (const int*)d_in[1];  // (2, E): src row then dst row
  const float* W1 = (const float*)d_in[2];
  const float* root1 = (const float*)d_in[3];
  const float* b1 = (const float*)d_in[4];
  const float* W2 = (const float*)d_in[5];
  const float* root2 = (const float*)d_in[6];
  const float* b2v = (const float*)d_in[7];
  float* out = (float*)d_out;

  const int* src = ei;
  const int* dstp = ei + NEDGE;

  // workspace layout (bytes), ~38.8 MB:
  // [bcnt 2K][boff 2K][gcursor 2K][degf N][agg1 16N] <- zeroed in one memset
  // [recs E][xw1 16N (reused as agg2)][xr1 16N][h 16N]
  char* w = (char*)d_ws;
  int* bcnt = (int*)w;           w += 2048;
  int* boff = (int*)w;           w += 2048;
  int* gcursor = (int*)w;        w += 2048;
  float* degf = (float*)w;       w += (size_t)N_NODES * 4;
  float* agg1 = (float*)w;       w += (size_t)N_NODES * HID * 4;
  unsigned* recs = (unsigned*)w; w += (size_t)NEDGE * 4;
  float* xw1 = (float*)w;        w += (size_t)N_NODES * HID * 4;
  float* xr1 = (float*)w;        w += (size_t)N_NODES * HID * 4;
  float* h = (float*)w;          w += (size_t)N_NODES * HID * 4;
  float* agg2 = xw1;  // xw1 dead after aggP<true>

  // zero bcnt..agg1 (6 KB + 6.8 MB) in one shot
  hipMemsetAsync(d_ws, 0, 6144 + (size_t)N_NODES * (1 + HID) * 4, stream);

  proj1_kernel<<<(N_NODES + 63) / 64, 256, 0, stream>>>(x, W1, root1, xw1,
                                                        xr1);
  histB_kernel<<<NCHUNK, 256, 0, stream>>>(dstp, bcnt);
  scan_kernel<<<1, 512, 0, stream>>>(bcnt, boff, gcursor);
  partA_kernel<<<NCHUNK, 256, 0, stream>>>(src, dstp, gcursor, recs);
  aggP_kernel<true><<<NBUCK * SLICES, 512, 0, stream>>>(boff, recs, xw1, agg1,
                                                        degf);
  hidden_kernel<<<(N_NODES * 4 + 255) / 256, 256, 0, stream>>>(
      (const float4*)agg1, (const float4*)xr1, b1, degf, (float4*)h);
  hipMemsetAsync(agg2, 0, (size_t)N_NODES * HID * 4, stream);
  aggP_kernel<false><<<NBUCK * SLICES, 512, 0, stream>>>(boff, recs, h, agg2,
                                                         nullptr);
  out_kernel<<<(N_NODES + 255) / 256, 256, 0, stream>>>(h, agg2, degf, W2,
                                                        root2, b2v, out);
}

// Round 10
// 356.831 us; speedup vs baseline: 2.3476x; 2.3476x over previous
//
#include <hip/hip_runtime.h>
#include <hip/hip_bf16.h>

#define N_NODES 100000
#define FIN 128
#define HID 16
#define NCLS 40
#define NEDGE 3200000
#define NBUCK 391     // ceil(100000/256): 256 dst-nodes per bucket
#define NCHUNK 782    // ceil(NEDGE/4096)
#define XS_LD 132
#define W_LD 132

__device__ __forceinline__ float4 f4add(float4 a, float4 b) {
  return make_float4(a.x + b.x, a.y + b.y, a.z + b.z, a.w + b.w);
}

// ---------------------------------------------------------------------------
// proj1: xw1 = x @ W1[1], xr1 = x @ root1 (both fp32). (unchanged, ~25 us)
// ---------------------------------------------------------------------------
__global__ __launch_bounds__(256) void proj1_kernel(
    const float* __restrict__ x, const float* __restrict__ W1,
    const float* __restrict__ root1,
    float* __restrict__ xw1, float* __restrict__ xr1) {
  __shared__ float xs[64 * XS_LD];
  __shared__ float WLt[32 * W_LD];

  int tid = threadIdx.x;
  int node0 = blockIdx.x * 64;

  for (int t = tid; t < 32 * FIN; t += 256) {
    int c = t >> 7, i = t & 127;
    WLt[c * W_LD + i] =
        (c < 16) ? W1[FIN * HID + i * HID + c] : root1[i * HID + (c - 16)];
  }
#pragma unroll
  for (int k = 0; k < 8; ++k) {
    int f = k * 256 + tid;
    int r = f >> 5;
    int cw = f & 31;
    float4 v = make_float4(0.f, 0.f, 0.f, 0.f);
    if (node0 + r < N_NODES)
      v = *(const float4*)(x + (size_t)(node0 + r) * FIN + cw * 4);
    *(float4*)(xs + r * XS_LD + cw * 4) = v;
  }
  __syncthreads();

  int tx = tid & 15;
  int ty = tid >> 4;
  const float* w0 = WLt + (2 * tx) * W_LD;
  const float* w1 = w0 + W_LD;
  const float* xrow = xs + (ty * 4) * XS_LD;

  float acc[4][2] = {{0.f, 0.f}, {0.f, 0.f}, {0.f, 0.f}, {0.f, 0.f}};
#pragma unroll 8
  for (int i = 0; i < FIN; i += 4) {
    float4 b0 = *(const float4*)(w0 + i);
    float4 b1v = *(const float4*)(w1 + i);
#pragma unroll
    for (int k = 0; k < 4; ++k) {
      float4 a = *(const float4*)(xrow + k * XS_LD + i);
      acc[k][0] += a.x * b0.x + a.y * b0.y + a.z * b0.z + a.w * b0.w;
      acc[k][1] += a.x * b1v.x + a.y * b1v.y + a.z * b1v.z + a.w * b1v.w;
    }
  }

  int c0 = 2 * tx;
#pragma unroll
  for (int k = 0; k < 4; ++k) {
    int n = node0 + ty * 4 + k;
    if (n < N_NODES) {
      float* dstp = (c0 < 16) ? (xw1 + n * HID + c0) : (xr1 + n * HID + c0 - 16);
      dstp[0] = acc[k][0];
      dstp[1] = acc[k][1];
    }
  }
}

// ---------------------------------------------------------------------------
// histB: bucket histogram (391 counters) with LDS pre-aggregation.
// ---------------------------------------------------------------------------
__global__ __launch_bounds__(256) void histB_kernel(
    const int* __restrict__ dst, int* __restrict__ bcnt) {
  __shared__ int hc[NBUCK];
  for (int t = threadIdx.x; t < NBUCK; t += 256) hc[t] = 0;
  __syncthreads();
  int base = blockIdx.x * 4096;
#pragma unroll
  for (int k = 0; k < 16; ++k) {
    int e = base + k * 256 + threadIdx.x;
    if (e < NEDGE) atomicAdd(&hc[dst[e] >> 8], 1);
  }
  __syncthreads();
  for (int t = threadIdx.x; t < NBUCK; t += 256) {
    int v = hc[t];
    if (v) atomicAdd(&bcnt[t], v);
  }
}

// ---------------------------------------------------------------------------
// scan: exclusive scan of 391 counts -> boff, gcursor; set sentinels.
// ---------------------------------------------------------------------------
__global__ __launch_bounds__(512) void scan_kernel(
    const int* __restrict__ bcnt, int* __restrict__ boff,
    int* __restrict__ gcursor, int* __restrict__ rowptr) {
  __shared__ int s[512];
  int v = (threadIdx.x < NBUCK) ? bcnt[threadIdx.x] : 0;
  s[threadIdx.x] = v;
  __syncthreads();
  for (int off = 1; off < 512; off <<= 1) {
    int t = (threadIdx.x >= off) ? s[threadIdx.x - off] : 0;
    __syncthreads();
    s[threadIdx.x] += t;
    __syncthreads();
  }
  if (threadIdx.x < NBUCK) {
    int e = s[threadIdx.x] - v;
    boff[threadIdx.x] = e;
    gcursor[threadIdx.x] = e;
  }
  if (threadIdx.x == 0) {
    boff[NBUCK] = NEDGE;
    rowptr[N_NODES] = NEDGE;
  }
}

// ---------------------------------------------------------------------------
// partA: multi-split partition, 4096-edge chunks (unchanged from R9, ~130 us).
// rec = src | (dst&255)<<17.
// ---------------------------------------------------------------------------
__global__ __launch_bounds__(256) void partA_kernel(
    const int* __restrict__ src, const int* __restrict__ dst,
    int* __restrict__ gcursor, unsigned* __restrict__ recs) {
  __shared__ int cnt[NBUCK];
  __shared__ int base[NBUCK];
  for (int t = threadIdx.x; t < NBUCK; t += 256) cnt[t] = 0;
  __syncthreads();

  int ebase = blockIdx.x * 4096;
  unsigned recv[16];
  int bk[16];
  int rank[16];
#pragma unroll
  for (int k = 0; k < 16; ++k) {
    int e = ebase + k * 256 + threadIdx.x;
    if (e < NEDGE) {
      int d = dst[e];
      bk[k] = d >> 8;
      recv[k] = (unsigned)src[e] | ((unsigned)(d & 255) << 17);
      rank[k] = atomicAdd(&cnt[bk[k]], 1);
    } else {
      bk[k] = -1;
    }
  }
  __syncthreads();
  for (int t = threadIdx.x; t < NBUCK; t += 256) {
    int cv = cnt[t];
    base[t] = cv ? atomicAdd(&gcursor[t], cv) : 0;
  }
  __syncthreads();
#pragma unroll
  for (int k = 0; k < 16; ++k)
    if (bk[k] >= 0) recs[base[bk[k]] + rank[k]] = recv[k];
}

// ---------------------------------------------------------------------------
// sortB: per-bucket counting sort -> full dst-sorted CSR (rowptr + colsrc).
// One block per bucket. Streams recs twice; LDS hist/scan/cursors.
// ---------------------------------------------------------------------------
__global__ __launch_bounds__(512) void sortB_kernel(
    const int* __restrict__ boff, const unsigned* __restrict__ recs,
    int* __restrict__ rowptr, int* __restrict__ colsrc) {
  __shared__ int hist[256];
  __shared__ int s[256];
  __shared__ int cur[256];
  if (threadIdx.x < 256) hist[threadIdx.x] = 0;
  __syncthreads();

  int b = blockIdx.x;
  int beg = boff[b], end = boff[b + 1];
  for (int j = beg + threadIdx.x; j < end; j += 512)
    atomicAdd(&hist[recs[j] >> 17], 1);
  __syncthreads();

  // inclusive scan of hist into s (first 256 threads; full-block barriers)
  if (threadIdx.x < 256) s[threadIdx.x] = hist[threadIdx.x];
  __syncthreads();
  for (int off = 1; off < 256; off <<= 1) {
    int t = 0;
    if (threadIdx.x < 256 && threadIdx.x >= off) t = s[threadIdx.x - off];
    __syncthreads();
    if (threadIdx.x < 256) s[threadIdx.x] += t;
    __syncthreads();
  }
  if (threadIdx.x < 256) {
    int excl = s[threadIdx.x] - hist[threadIdx.x];
    int n = b * 256 + threadIdx.x;
    if (n < N_NODES) rowptr[n] = beg + excl;
    cur[threadIdx.x] = excl;
  }
  __syncthreads();

  for (int j = beg + threadIdx.x; j < end; j += 512) {
    unsigned r = recs[j];
    int dl = r >> 17;
    int pos = atomicAdd(&cur[dl], 1);
    colsrc[beg + pos] = (int)(r & 0x1FFFF);
  }
}

// ---------------------------------------------------------------------------
// gather1: CSR gather, 4 lanes per node, float4 register accumulation.
// No atomics, no LDS. Fused mean + xr1 + b1 + ELU epilogue -> h (fp32).
// ---------------------------------------------------------------------------
__global__ __launch_bounds__(256) void gather1_kernel(
    const int* __restrict__ rowptr, const int* __restrict__ colsrc,
    const float4* __restrict__ val4, const float4* __restrict__ xr14,
    const float* __restrict__ b1, float4* __restrict__ h4) {
  int t = blockIdx.x * 256 + threadIdx.x;
  int n = t >> 2;
  int q = t & 3;
  if (n >= N_NODES) return;
  int beg = rowptr[n], end = rowptr[n + 1];
  float4 acc = make_float4(0.f, 0.f, 0.f, 0.f);
  int j = beg;
  // head to 16B-aligned colsrc
  for (; j < end && (j & 3); ++j) acc = f4add(acc, val4[colsrc[j] * 4 + q]);
  // body: int4 col loads + 4 independent float4 gathers
  for (; j + 4 <= end; j += 4) {
    int4 cs = *(const int4*)(colsrc + j);
    float4 v0 = val4[cs.x * 4 + q];
    float4 v1 = val4[cs.y * 4 + q];
    float4 v2 = val4[cs.z * 4 + q];
    float4 v3 = val4[cs.w * 4 + q];
    acc = f4add(acc, f4add(f4add(v0, v1), f4add(v2, v3)));
  }
  for (; j < end; ++j) acc = f4add(acc, val4[colsrc[j] * 4 + q]);

  float inv = 1.0f / fmaxf((float)(end - beg), 1.0f);
  float4 r = xr14[n * 4 + q];
  const float4 bb = *(const float4*)(b1 + q * 4);
  float4 o;
  o.x = acc.x * inv + r.x + bb.x;
  o.y = acc.y * inv + r.y + bb.y;
  o.z = acc.z * inv + r.z + bb.z;
  o.w = acc.w * inv + r.w + bb.w;
  o.x = (o.x > 0.f) ? o.x : expm1f(o.x);
  o.y = (o.y > 0.f) ? o.y : expm1f(o.y);
  o.z = (o.z > 0.f) ? o.z : expm1f(o.z);
  o.w = (o.w > 0.f) ? o.w : expm1f(o.w);
  h4[n * 4 + q] = o;
}

// ---------------------------------------------------------------------------
// gather2: same CSR gather over h; writes mean-normalized agg2n (fp32).
// ---------------------------------------------------------------------------
__global__ __launch_bounds__(256) void gather2_kernel(
    const int* __restrict__ rowptr, const int* __restrict__ colsrc,
    const float4* __restrict__ val4, float4* __restrict__ agg2n4) {
  int t = blockIdx.x * 256 + threadIdx.x;
  int n = t >> 2;
  int q = t & 3;
  if (n >= N_NODES) return;
  int beg = rowptr[n], end = rowptr[n + 1];
  float4 acc = make_float4(0.f, 0.f, 0.f, 0.f);
  int j = beg;
  for (; j < end && (j & 3); ++j) acc = f4add(acc, val4[colsrc[j] * 4 + q]);
  for (; j + 4 <= end; j += 4) {
    int4 cs = *(const int4*)(colsrc + j);
    float4 v0 = val4[cs.x * 4 + q];
    float4 v1 = val4[cs.y * 4 + q];
    float4 v2 = val4[cs.z * 4 + q];
    float4 v3 = val4[cs.w * 4 + q];
    acc = f4add(acc, f4add(f4add(v0, v1), f4add(v2, v3)));
  }
  for (; j < end; ++j) acc = f4add(acc, val4[colsrc[j] * 4 + q]);

  float inv = 1.0f / fmaxf((float)(end - beg), 1.0f);
  agg2n4[n * 4 + q] = make_float4(acc.x * inv, acc.y * inv, acc.z * inv,
                                  acc.w * inv);
}

// ---------------------------------------------------------------------------
// out: agg2n @ W2[1] + h @ root2 + b2, log_softmax, fp32 store.
// (agg2n already mean-normalized)
// ---------------------------------------------------------------------------
__global__ __launch_bounds__(256) void out_kernel(
    const float* __restrict__ h, const float* __restrict__ agg2n,
    const float* __restrict__ W2, const float* __restrict__ root2,
    const float* __restrict__ b2v, float* __restrict__ out) {
  __shared__ float Wl[HID * NCLS];
  __shared__ float Rl[HID * NCLS];
  __shared__ float Bl[NCLS];
  for (int i = threadIdx.x; i < HID * NCLS; i += blockDim.x) {
    Wl[i] = W2[HID * NCLS + i];
    Rl[i] = root2[i];
  }
  if (threadIdx.x < NCLS) Bl[threadIdx.x] = b2v[threadIdx.x];
  __syncthreads();

  int n = blockIdx.x * blockDim.x + threadIdx.x;
  if (n >= N_NODES) return;

  float hv[HID], av[HID];
#pragma unroll
  for (int c = 0; c < HID; ++c) {
    hv[c] = h[n * HID + c];
    av[c] = agg2n[n * HID + c];
  }
  float logit[NCLS];
#pragma unroll
  for (int j = 0; j < NCLS; ++j) logit[j] = Bl[j];
  for (int c = 0; c < HID; ++c) {
    float hc = hv[c], ac = av[c];
#pragma unroll
    for (int j = 0; j < NCLS; ++j)
      logit[j] += ac * Wl[c * NCLS + j] + hc * Rl[c * NCLS + j];
  }
  float m = -INFINITY;
#pragma unroll
  for (int j = 0; j < NCLS; ++j) m = fmaxf(m, logit[j]);
  float s = 0.f;
#pragma unroll
  for (int j = 0; j < NCLS; ++j) s += expf(logit[j] - m);
  float lse = m + logf(s);
#pragma unroll
  for (int j = 0; j < NCLS; ++j)
    out[(size_t)n * NCLS + j] = logit[j] - lse;
}

extern "C" void kernel_launch(void* const* d_in, const int* in_sizes, int n_in,
                              void* d_out, int out_size, void* d_ws,
                              size_t ws_size, hipStream_t stream) {
  const float* x = (const float*)d_in[0];
  const int* ei = (const int*)d_in[1];  // (2, E): src row then dst row
  const float* W1 = (const float*)d_in[2];
  const float* root1 = (const float*)d_in[3];
  const float* b1 = (const float*)d_in[4];
  const float* W2 = (const float*)d_in[5];
  const float* root2 = (const float*)d_in[6];
  const float* b2v = (const float*)d_in[7];
  float* out = (float*)d_out;

  const int* src = ei;
  const int* dstp = ei + NEDGE;

  // workspace (bytes), ~38.8 MB (R9-proven footprint):
  // [bcnt 2K][boff 2K][gcursor 2K][rowptr (N+4)*4][recs E*4 (reused as h)]
  // [colsrc E*4][xw1 16N*4 (reused as agg2n)][xr1 16N*4]
  char* w = (char*)d_ws;
  int* bcnt = (int*)w;           w += 2048;
  int* boff = (int*)w;           w += 2048;
  int* gcursor = (int*)w;        w += 2048;
  int* rowptr = (int*)w;         w += (size_t)(N_NODES + 4) * 4;
  unsigned* recs = (unsigned*)w; w += (size_t)NEDGE * 4;
  int* colsrc = (int*)w;         w += (size_t)NEDGE * 4;
  float* xw1 = (float*)w;        w += (size_t)N_NODES * HID * 4;
  float* xr1 = (float*)w;        w += (size_t)N_NODES * HID * 4;
  float* h = (float*)recs;   // recs dead after sortB
  float* agg2n = xw1;        // xw1 dead after gather1

  hipMemsetAsync(bcnt, 0, 2048, stream);

  proj1_kernel<<<(N_NODES + 63) / 64, 256, 0, stream>>>(x, W1, root1, xw1,
                                                        xr1);
  histB_kernel<<<NCHUNK, 256, 0, stream>>>(dstp, bcnt);
  scan_kernel<<<1, 512, 0, stream>>>(bcnt, boff, gcursor, rowptr);
  partA_kernel<<<NCHUNK, 256, 0, stream>>>(src, dstp, gcursor, recs);
  sortB_kernel<<<NBUCK, 512, 0, stream>>>(boff, recs, rowptr, colsrc);
  gather1_kernel<<<(N_NODES * 4 + 255) / 256, 256, 0, stream>>>(
      rowptr, colsrc, (const float4*)xw1, (const float4*)xr1, b1, (float4*)h);
  gather2_kernel<<<(N_NODES * 4 + 255) / 256, 256, 0, stream>>>(
      rowptr, colsrc, (const float4*)h, (float4*)agg2n);
  out_kernel<<<(N_NODES + 255) / 256, 256, 0, stream>>>(h, agg2n, W2, root2,
                                                        b2v, out);
}